// Round 2
// baseline (307.968 us; speedup 1.0000x reference)
//
#include <hip/hip_runtime.h>
#include <hip/hip_bf16.h>
#include <math.h>

#define BB 256
#define SS 128
#define DD 768
#define K2 1536
#define MASK_ID 103

typedef __attribute__((ext_vector_type(8))) short short8;
typedef __attribute__((ext_vector_type(4))) float floatx4;

__constant__ int c_ids[21] = {
    2307, 2204, 3835, 2157, 6581, 2986, 5151, 3893,   // g0 (8)
    7929, 24791, 8699, 4257, 16021, 6623,             // g1 (6)
    6659, 2919, 11771, 3532, 11325, 4997, 13135       // g2 (7)
};

__device__ __forceinline__ float waveReduceSum(float v) {       // lane0 holds sum
    #pragma unroll
    for (int off = 32; off > 0; off >>= 1) v += __shfl_down(v, off, 64);
    return v;
}
__device__ __forceinline__ unsigned short f2bf(float f) {   // RNE
    unsigned int u = __float_as_uint(f);
    u += 0x7FFF + ((u >> 16) & 1);
    return (unsigned short)(u >> 16);
}

// Kernel 1: per-batch, 1024 threads = 16 waves. (unchanged from R1 — passed)
//  - prologue: grid-stride fp32->bf16 convert of dense_w
//  - single pass over valid rows with online softmax; 4-row ILP per wave.
__global__ __launch_bounds__(1024) void k_att(
    const float* __restrict__ bert, const int* __restrict__ ids,
    const int* __restrict__ len, const float* __restrict__ senti_w,
    const float* __restrict__ senti_b, float* __restrict__ cat_out,
    unsigned short* __restrict__ feats,
    const float* __restrict__ dense_w, unsigned short* __restrict__ dwb)
{
    __shared__ __align__(16) float s_mask[DD];
    __shared__ __align__(16) float s_part[16][DD];   // per-wave att partials
    __shared__ float s_m[16], s_l[16], s_scale[16];
    __shared__ float s_red[32];
    __shared__ float s_M;
    __shared__ int s_mp;

    const int b = blockIdx.x;
    const int tid = threadIdx.x;
    const int lane = tid & 63;
    const int wave = tid >> 6;     // 0..15

    if (tid == 0) s_mp = SS;

    // fused dense_w fp32 -> bf16 (n4 = 294912 float4s over 262144 threads)
    {
        const int n4 = DD * K2 / 4;
        for (int i = b * 1024 + tid; i < n4; i += BB * 1024) {
            float4 v = ((const float4*)dense_w)[i];
            ushort4 o;
            o.x = f2bf(v.x); o.y = f2bf(v.y); o.z = f2bf(v.z); o.w = f2bf(v.w);
            ((ushort4*)dwb)[i] = o;
        }
    }

    __syncthreads();
    if (tid < SS && ids[b * SS + tid] == MASK_ID) atomicMin(&s_mp, tid);
    __syncthreads();
    const int mp = (s_mp == SS) ? 0 : s_mp;   // argmax of all-False -> 0
    const int L = len[b];
    const float* base = bert + (size_t)b * SS * DD;
    const float* mrow = base + (size_t)mp * DD;

    // mask row -> LDS; category dot on pooler (row 0)
    float c0 = 0.f, c1 = 0.f;
    if (tid < DD) {
        s_mask[tid] = mrow[tid];
        float x = base[tid];
        c0 = x * senti_w[tid];
        c1 = x * senti_w[DD + tid];
    }
    c0 = waveReduceSum(c0);
    c1 = waveReduceSum(c1);
    if (lane == 0) { s_red[wave] = c0; s_red[16 + wave] = c1; }
    __syncthreads();
    if (tid == 0) {
        float t0 = 0.f, t1 = 0.f;
        #pragma unroll
        for (int w = 0; w < 16; ++w) { t0 += s_red[w]; t1 += s_red[16 + w]; }
        cat_out[b * 2 + 0] = t0 + senti_b[0];
        cat_out[b * 2 + 1] = t1 + senti_b[1];
    }

    const float4* m4 = (const float4*)s_mask;
    float4 mm0 = m4[lane], mm1 = m4[lane + 64], mm2 = m4[lane + 128];
    float4 A0 = {0,0,0,0}, A1 = {0,0,0,0}, A2 = {0,0,0,0};
    float mloc = -INFINITY, lloc = 0.f;
    const int end = 3 + L;
    int s = 3 + wave;
    for (; s + 48 < end; s += 64) {
        const float4* r0 = (const float4*)(base + (size_t)s * DD);
        const float4* r1 = (const float4*)(base + (size_t)(s + 16) * DD);
        const float4* r2 = (const float4*)(base + (size_t)(s + 32) * DD);
        const float4* r3 = (const float4*)(base + (size_t)(s + 48) * DD);
        float4 a0 = r0[lane], a1 = r0[lane + 64], a2 = r0[lane + 128];
        float4 b0 = r1[lane], b1 = r1[lane + 64], b2 = r1[lane + 128];
        float4 c0v = r2[lane], c1v = r2[lane + 64], c2v = r2[lane + 128];
        float4 e0 = r3[lane], e1 = r3[lane + 64], e2 = r3[lane + 128];
        float d1 = a0.x*mm0.x + a0.y*mm0.y + a0.z*mm0.z + a0.w*mm0.w
                 + a1.x*mm1.x + a1.y*mm1.y + a1.z*mm1.z + a1.w*mm1.w
                 + a2.x*mm2.x + a2.y*mm2.y + a2.z*mm2.z + a2.w*mm2.w;
        float d2 = b0.x*mm0.x + b0.y*mm0.y + b0.z*mm0.z + b0.w*mm0.w
                 + b1.x*mm1.x + b1.y*mm1.y + b1.z*mm1.z + b1.w*mm1.w
                 + b2.x*mm2.x + b2.y*mm2.y + b2.z*mm2.z + b2.w*mm2.w;
        float d3 = c0v.x*mm0.x + c0v.y*mm0.y + c0v.z*mm0.z + c0v.w*mm0.w
                 + c1v.x*mm1.x + c1v.y*mm1.y + c1v.z*mm1.z + c1v.w*mm1.w
                 + c2v.x*mm2.x + c2v.y*mm2.y + c2v.z*mm2.z + c2v.w*mm2.w;
        float d4 = e0.x*mm0.x + e0.y*mm0.y + e0.z*mm0.z + e0.w*mm0.w
                 + e1.x*mm1.x + e1.y*mm1.y + e1.z*mm1.z + e1.w*mm1.w
                 + e2.x*mm2.x + e2.y*mm2.y + e2.z*mm2.z + e2.w*mm2.w;
        #pragma unroll
        for (int off = 32; off > 0; off >>= 1) {    // 4-way interleaved reduce
            d1 += __shfl_xor(d1, off, 64);
            d2 += __shfl_xor(d2, off, 64);
            d3 += __shfl_xor(d3, off, 64);
            d4 += __shfl_xor(d4, off, 64);
        }
        float mnew = fmaxf(fmaxf(fmaxf(d1, d2), fmaxf(d3, d4)), mloc);
        float scale = __expf(mloc - mnew);   // first iter: exp(-inf)=0
        float p1 = __expf(d1 - mnew);
        float p2 = __expf(d2 - mnew);
        float p3 = __expf(d3 - mnew);
        float p4 = __expf(d4 - mnew);
        lloc = lloc * scale + p1 + p2 + p3 + p4;
        A0.x = A0.x*scale + p1*a0.x + p2*b0.x + p3*c0v.x + p4*e0.x;
        A0.y = A0.y*scale + p1*a0.y + p2*b0.y + p3*c0v.y + p4*e0.y;
        A0.z = A0.z*scale + p1*a0.z + p2*b0.z + p3*c0v.z + p4*e0.z;
        A0.w = A0.w*scale + p1*a0.w + p2*b0.w + p3*c0v.w + p4*e0.w;
        A1.x = A1.x*scale + p1*a1.x + p2*b1.x + p3*c1v.x + p4*e1.x;
        A1.y = A1.y*scale + p1*a1.y + p2*b1.y + p3*c1v.y + p4*e1.y;
        A1.z = A1.z*scale + p1*a1.z + p2*b1.z + p3*c1v.z + p4*e1.z;
        A1.w = A1.w*scale + p1*a1.w + p2*b1.w + p3*c1v.w + p4*e1.w;
        A2.x = A2.x*scale + p1*a2.x + p2*b2.x + p3*c2v.x + p4*e2.x;
        A2.y = A2.y*scale + p1*a2.y + p2*b2.y + p3*c2v.y + p4*e2.y;
        A2.z = A2.z*scale + p1*a2.z + p2*b2.z + p3*c2v.z + p4*e2.z;
        A2.w = A2.w*scale + p1*a2.w + p2*b2.w + p3*c2v.w + p4*e2.w;
        mloc = mnew;
    }
    for (; s + 16 < end; s += 32) {
        const float4* ra = (const float4*)(base + (size_t)s * DD);
        const float4* rb = (const float4*)(base + (size_t)(s + 16) * DD);
        float4 a0 = ra[lane], a1 = ra[lane + 64], a2 = ra[lane + 128];
        float4 b0 = rb[lane], b1 = rb[lane + 64], b2 = rb[lane + 128];
        float d1 = a0.x*mm0.x + a0.y*mm0.y + a0.z*mm0.z + a0.w*mm0.w
                 + a1.x*mm1.x + a1.y*mm1.y + a1.z*mm1.z + a1.w*mm1.w
                 + a2.x*mm2.x + a2.y*mm2.y + a2.z*mm2.z + a2.w*mm2.w;
        float d2 = b0.x*mm0.x + b0.y*mm0.y + b0.z*mm0.z + b0.w*mm0.w
                 + b1.x*mm1.x + b1.y*mm1.y + b1.z*mm1.z + b1.w*mm1.w
                 + b2.x*mm2.x + b2.y*mm2.y + b2.z*mm2.z + b2.w*mm2.w;
        #pragma unroll
        for (int off = 32; off > 0; off >>= 1) {    // 2-way interleaved reduce
            d1 += __shfl_xor(d1, off, 64);
            d2 += __shfl_xor(d2, off, 64);
        }
        float mnew = fmaxf(mloc, fmaxf(d1, d2));
        float scale = __expf(mloc - mnew);
        float p1 = __expf(d1 - mnew);
        float p2 = __expf(d2 - mnew);
        lloc = lloc * scale + p1 + p2;
        A0.x = A0.x*scale + p1*a0.x + p2*b0.x; A0.y = A0.y*scale + p1*a0.y + p2*b0.y;
        A0.z = A0.z*scale + p1*a0.z + p2*b0.z; A0.w = A0.w*scale + p1*a0.w + p2*b0.w;
        A1.x = A1.x*scale + p1*a1.x + p2*b1.x; A1.y = A1.y*scale + p1*a1.y + p2*b1.y;
        A1.z = A1.z*scale + p1*a1.z + p2*b1.z; A1.w = A1.w*scale + p1*a1.w + p2*b1.w;
        A2.x = A2.x*scale + p1*a2.x + p2*b2.x; A2.y = A2.y*scale + p1*a2.y + p2*b2.y;
        A2.z = A2.z*scale + p1*a2.z + p2*b2.z; A2.w = A2.w*scale + p1*a2.w + p2*b2.w;
        mloc = mnew;
    }
    for (; s < end; s += 16) {
        const float4* ra = (const float4*)(base + (size_t)s * DD);
        float4 a0 = ra[lane], a1 = ra[lane + 64], a2 = ra[lane + 128];
        float d1 = a0.x*mm0.x + a0.y*mm0.y + a0.z*mm0.z + a0.w*mm0.w
                 + a1.x*mm1.x + a1.y*mm1.y + a1.z*mm1.z + a1.w*mm1.w
                 + a2.x*mm2.x + a2.y*mm2.y + a2.z*mm2.z + a2.w*mm2.w;
        #pragma unroll
        for (int off = 32; off > 0; off >>= 1) d1 += __shfl_xor(d1, off, 64);
        float mnew = fmaxf(mloc, d1);
        float scale = __expf(mloc - mnew);
        float p1 = __expf(d1 - mnew);
        lloc = lloc * scale + p1;
        A0.x = A0.x*scale + p1*a0.x; A0.y = A0.y*scale + p1*a0.y;
        A0.z = A0.z*scale + p1*a0.z; A0.w = A0.w*scale + p1*a0.w;
        A1.x = A1.x*scale + p1*a1.x; A1.y = A1.y*scale + p1*a1.y;
        A1.z = A1.z*scale + p1*a1.z; A1.w = A1.w*scale + p1*a1.w;
        A2.x = A2.x*scale + p1*a2.x; A2.y = A2.y*scale + p1*a2.y;
        A2.z = A2.z*scale + p1*a2.z; A2.w = A2.w*scale + p1*a2.w;
        mloc = mnew;
    }
    if (lane == 0) { s_m[wave] = mloc; s_l[wave] = lloc; }
    float4* pw = (float4*)s_part[wave];
    pw[lane] = A0; pw[lane + 64] = A1; pw[lane + 128] = A2;
    __syncthreads();

    // combine 16 wave-partials
    if (tid == 0) {
        float M = -INFINITY;
        #pragma unroll
        for (int w = 0; w < 16; ++w) M = fmaxf(M, s_m[w]);
        s_M = M;
    }
    __syncthreads();
    if (tid < 16) s_scale[tid] = __expf(s_m[tid] - s_M);  // empty wave -> 0
    __syncthreads();

    if (tid < DD) {
        float lt = 0.f, a = 0.f;
        #pragma unroll
        for (int w = 0; w < 16; ++w) {
            lt += s_scale[w] * s_l[w];
            a  += s_scale[w] * s_part[w][tid];
        }
        unsigned short* fb = feats + (size_t)b * K2;
        fb[tid]      = f2bf(a / lt);
        fb[DD + tid] = f2bf(s_mask[tid]);
    }
}

// Kernel 2 (fused dense+dec): batch-major blocking. 16 blocks x 16 batches.
// Each block: MFMA h[16][768] tile -> LDS (never global), then 21 decoder
// dots + tiny matmuls in-block. Removes the k_dec kernel, its launch gap,
// and the h global round-trip.
#define HP 772   // padded h row (768+4): breaks 768%32==0 bank aliasing
__global__ __launch_bounds__(1024) void k_dd(
    const unsigned short* __restrict__ featsb,
    const unsigned short* __restrict__ dwb,
    const float* __restrict__ db,
    const float* __restrict__ dec_w, const float* __restrict__ dec_b,
    const float* __restrict__ w0, const float* __restrict__ w1,
    const float* __restrict__ w2, float* __restrict__ out)
{
    __shared__ __align__(16) float s_h[16][HP];   // ~48 KB
    __shared__ float s_p[16][21];
    const int tid = threadIdx.x;
    const int lane = tid & 63, wave = tid >> 6;   // 0..15
    const int b0 = blockIdx.x * 16;
    const int m = lane & 15, q = lane >> 4;

    // Each wave owns j-range [wave*48, wave*48+48): 3 j-tiles of 16, full K.
    // Interleaved accumulator chains (3 independent) hide MFMA latency.
    const int j0 = wave * 48;
    const short8* Arow = (const short8*)(featsb + (size_t)(b0 + m) * K2);
    const short8* B0 = (const short8*)(dwb + (size_t)(j0      + m) * K2);
    const short8* B1 = (const short8*)(dwb + (size_t)(j0 + 16 + m) * K2);
    const short8* B2 = (const short8*)(dwb + (size_t)(j0 + 32 + m) * K2);
    floatx4 ac0 = {0,0,0,0}, ac1 = {0,0,0,0}, ac2 = {0,0,0,0};
    #pragma unroll 2
    for (int k8 = 0; k8 < 192; k8 += 4) {   // 48 K-steps of 32
        short8 a = Arow[k8 + q];
        ac0 = __builtin_amdgcn_mfma_f32_16x16x32_bf16(a, B0[k8 + q], ac0, 0, 0, 0);
        ac1 = __builtin_amdgcn_mfma_f32_16x16x32_bf16(a, B1[k8 + q], ac1, 0, 0, 0);
        ac2 = __builtin_amdgcn_mfma_f32_16x16x32_bf16(a, B2[k8 + q], ac2, 0, 0, 0);
    }
    // C/D layout: col = lane&15 (B row index j), row = q*4 + r (A row index b)
    {
        const int rb = q * 4;
        const float d0 = db[j0 + m], d1 = db[j0 + 16 + m], d2 = db[j0 + 32 + m];
        #pragma unroll
        for (int r = 0; r < 4; ++r) {
            s_h[rb + r][j0 + m]      = tanhf(ac0[r] + d0);
            s_h[rb + r][j0 + 16 + m] = tanhf(ac1[r] + d1);
            s_h[rb + r][j0 + 32 + m] = tanhf(ac2[r] + d2);
        }
    }
    __syncthreads();

    // wave w: decoder dots for batch b0+w (h row w in LDS)
    {
        const float4* h4 = (const float4*)s_h[wave];
        float4 x0 = h4[lane], x1 = h4[lane + 64], x2 = h4[lane + 128];
        for (int v = 0; v < 21; ++v) {
            const int vid = c_ids[v];
            const float4* wr = (const float4*)(dec_w + (size_t)vid * DD);
            float4 v0 = wr[lane], v1 = wr[lane + 64], v2 = wr[lane + 128];
            float acc = x0.x*v0.x + x0.y*v0.y + x0.z*v0.z + x0.w*v0.w
                      + x1.x*v1.x + x1.y*v1.y + x1.z*v1.z + x1.w*v1.w
                      + x2.x*v2.x + x2.y*v2.y + x2.z*v2.z + x2.w*v2.w;
            acc = waveReduceSum(acc);
            if (lane == 0) s_p[wave][v] = tanhf(acc + dec_b[vid]);
        }
    }
    __syncthreads();

    // 96 threads: out[b][c][g] for the block's 16 batches
    if (tid < 96) {
        const int bi = tid / 6, r6 = tid % 6;
        const int c = r6 / 3, g = r6 % 3;
        const float* wg = (g == 0) ? w0 : (g == 1) ? w1 : w2;
        const int n    = (g == 0) ? 8  : (g == 1) ? 6  : 7;
        const int base = (g == 0) ? 0  : (g == 1) ? 8  : 14;
        float acc = 0.f;
        for (int i = 0; i < n; ++i) acc += s_p[bi][base + i] * wg[c * n + i];
        out[(size_t)(b0 + bi) * 6 + c * 3 + g] = acc;
    }
}

extern "C" void kernel_launch(void* const* d_in, const int* in_sizes, int n_in,
                              void* d_out, int out_size, void* d_ws, size_t ws_size,
                              hipStream_t stream) {
    const float* bert    = (const float*)d_in[0];
    const int*   ids     = (const int*)  d_in[1];
    const int*   len     = (const int*)  d_in[2];
    const float* senti_w = (const float*)d_in[3];
    const float* senti_b = (const float*)d_in[4];
    const float* dense_w = (const float*)d_in[5];
    const float* dense_b = (const float*)d_in[6];
    const float* dec_w   = (const float*)d_in[7];
    const float* dec_b   = (const float*)d_in[8];
    const float* w0      = (const float*)d_in[9];
    const float* w1      = (const float*)d_in[10];
    const float* w2      = (const float*)d_in[11];
    float* out = (float*)d_out;

    // ws layout (16B aligned chunks)
    unsigned short* feats = (unsigned short*)d_ws;            // B x 1536 bf16
    unsigned short* dwb   = feats + (size_t)BB * K2;          // 768x1536 bf16

    k_att<<<BB, 1024, 0, stream>>>(bert, ids, len, senti_w, senti_b, out,
                                   feats, dense_w, dwb);
    k_dd<<<16, 1024, 0, stream>>>(feats, dwb, dense_b, dec_w, dec_b,
                                  w0, w1, w2, out + BB * 2);
}

// Round 4
// 220.605 us; speedup vs baseline: 1.3960x; 1.3960x over previous
//
#include <hip/hip_runtime.h>
#include <hip/hip_bf16.h>
#include <math.h>

#define BB 256
#define SS 128
#define DD 768
#define K2 1536
#define MASK_ID 103

typedef __attribute__((ext_vector_type(8))) short short8;
typedef __attribute__((ext_vector_type(4))) float floatx4;

__constant__ int c_ids[21] = {
    2307, 2204, 3835, 2157, 6581, 2986, 5151, 3893,   // g0 (8)
    7929, 24791, 8699, 4257, 16021, 6623,             // g1 (6)
    6659, 2919, 11771, 3532, 11325, 4997, 13135       // g2 (7)
};

__device__ __forceinline__ float waveReduceSum(float v) {       // lane0 holds sum
    #pragma unroll
    for (int off = 32; off > 0; off >>= 1) v += __shfl_down(v, off, 64);
    return v;
}
__device__ __forceinline__ unsigned short f2bf(float f) {   // RNE
    unsigned int u = __float_as_uint(f);
    u += 0x7FFF + ((u >> 16) & 1);
    return (unsigned short)(u >> 16);
}

// Kernel 1: per-batch, 1024 threads = 16 waves. (R1-verified)
//  - prologue: grid-stride fp32->bf16 convert of dense_w
//  - single pass over valid rows with online softmax; 4-row ILP per wave.
__global__ __launch_bounds__(1024) void k_att(
    const float* __restrict__ bert, const int* __restrict__ ids,
    const int* __restrict__ len, const float* __restrict__ senti_w,
    const float* __restrict__ senti_b, float* __restrict__ cat_out,
    unsigned short* __restrict__ feats,
    const float* __restrict__ dense_w, unsigned short* __restrict__ dwb)
{
    __shared__ __align__(16) float s_mask[DD];
    __shared__ __align__(16) float s_part[16][DD];   // per-wave att partials
    __shared__ float s_m[16], s_l[16], s_scale[16];
    __shared__ float s_red[32];
    __shared__ float s_M;
    __shared__ int s_mp;

    const int b = blockIdx.x;
    const int tid = threadIdx.x;
    const int lane = tid & 63;
    const int wave = tid >> 6;     // 0..15

    if (tid == 0) s_mp = SS;

    // fused dense_w fp32 -> bf16 (n4 = 294912 float4s over 262144 threads)
    {
        const int n4 = DD * K2 / 4;
        for (int i = b * 1024 + tid; i < n4; i += BB * 1024) {
            float4 v = ((const float4*)dense_w)[i];
            ushort4 o;
            o.x = f2bf(v.x); o.y = f2bf(v.y); o.z = f2bf(v.z); o.w = f2bf(v.w);
            ((ushort4*)dwb)[i] = o;
        }
    }

    __syncthreads();
    if (tid < SS && ids[b * SS + tid] == MASK_ID) atomicMin(&s_mp, tid);
    __syncthreads();
    const int mp = (s_mp == SS) ? 0 : s_mp;   // argmax of all-False -> 0
    const int L = len[b];
    const float* base = bert + (size_t)b * SS * DD;
    const float* mrow = base + (size_t)mp * DD;

    // mask row -> LDS; category dot on pooler (row 0)
    float c0 = 0.f, c1 = 0.f;
    if (tid < DD) {
        s_mask[tid] = mrow[tid];
        float x = base[tid];
        c0 = x * senti_w[tid];
        c1 = x * senti_w[DD + tid];
    }
    c0 = waveReduceSum(c0);
    c1 = waveReduceSum(c1);
    if (lane == 0) { s_red[wave] = c0; s_red[16 + wave] = c1; }
    __syncthreads();
    if (tid == 0) {
        float t0 = 0.f, t1 = 0.f;
        #pragma unroll
        for (int w = 0; w < 16; ++w) { t0 += s_red[w]; t1 += s_red[16 + w]; }
        cat_out[b * 2 + 0] = t0 + senti_b[0];
        cat_out[b * 2 + 1] = t1 + senti_b[1];
    }

    const float4* m4 = (const float4*)s_mask;
    float4 mm0 = m4[lane], mm1 = m4[lane + 64], mm2 = m4[lane + 128];
    float4 A0 = {0,0,0,0}, A1 = {0,0,0,0}, A2 = {0,0,0,0};
    float mloc = -INFINITY, lloc = 0.f;
    const int end = 3 + L;
    int s = 3 + wave;
    for (; s + 48 < end; s += 64) {
        const float4* r0 = (const float4*)(base + (size_t)s * DD);
        const float4* r1 = (const float4*)(base + (size_t)(s + 16) * DD);
        const float4* r2 = (const float4*)(base + (size_t)(s + 32) * DD);
        const float4* r3 = (const float4*)(base + (size_t)(s + 48) * DD);
        float4 a0 = r0[lane], a1 = r0[lane + 64], a2 = r0[lane + 128];
        float4 b0 = r1[lane], b1 = r1[lane + 64], b2 = r1[lane + 128];
        float4 c0v = r2[lane], c1v = r2[lane + 64], c2v = r2[lane + 128];
        float4 e0 = r3[lane], e1 = r3[lane + 64], e2 = r3[lane + 128];
        float d1 = a0.x*mm0.x + a0.y*mm0.y + a0.z*mm0.z + a0.w*mm0.w
                 + a1.x*mm1.x + a1.y*mm1.y + a1.z*mm1.z + a1.w*mm1.w
                 + a2.x*mm2.x + a2.y*mm2.y + a2.z*mm2.z + a2.w*mm2.w;
        float d2 = b0.x*mm0.x + b0.y*mm0.y + b0.z*mm0.z + b0.w*mm0.w
                 + b1.x*mm1.x + b1.y*mm1.y + b1.z*mm1.z + b1.w*mm1.w
                 + b2.x*mm2.x + b2.y*mm2.y + b2.z*mm2.z + b2.w*mm2.w;
        float d3 = c0v.x*mm0.x + c0v.y*mm0.y + c0v.z*mm0.z + c0v.w*mm0.w
                 + c1v.x*mm1.x + c1v.y*mm1.y + c1v.z*mm1.z + c1v.w*mm1.w
                 + c2v.x*mm2.x + c2v.y*mm2.y + c2v.z*mm2.z + c2v.w*mm2.w;
        float d4 = e0.x*mm0.x + e0.y*mm0.y + e0.z*mm0.z + e0.w*mm0.w
                 + e1.x*mm1.x + e1.y*mm1.y + e1.z*mm1.z + e1.w*mm1.w
                 + e2.x*mm2.x + e2.y*mm2.y + e2.z*mm2.z + e2.w*mm2.w;
        #pragma unroll
        for (int off = 32; off > 0; off >>= 1) {    // 4-way interleaved reduce
            d1 += __shfl_xor(d1, off, 64);
            d2 += __shfl_xor(d2, off, 64);
            d3 += __shfl_xor(d3, off, 64);
            d4 += __shfl_xor(d4, off, 64);
        }
        float mnew = fmaxf(fmaxf(fmaxf(d1, d2), fmaxf(d3, d4)), mloc);
        float scale = __expf(mloc - mnew);   // first iter: exp(-inf)=0
        float p1 = __expf(d1 - mnew);
        float p2 = __expf(d2 - mnew);
        float p3 = __expf(d3 - mnew);
        float p4 = __expf(d4 - mnew);
        lloc = lloc * scale + p1 + p2 + p3 + p4;
        A0.x = A0.x*scale + p1*a0.x + p2*b0.x + p3*c0v.x + p4*e0.x;
        A0.y = A0.y*scale + p1*a0.y + p2*b0.y + p3*c0v.y + p4*e0.y;
        A0.z = A0.z*scale + p1*a0.z + p2*b0.z + p3*c0v.z + p4*e0.z;
        A0.w = A0.w*scale + p1*a0.w + p2*b0.w + p3*c0v.w + p4*e0.w;
        A1.x = A1.x*scale + p1*a1.x + p2*b1.x + p3*c1v.x + p4*e1.x;
        A1.y = A1.y*scale + p1*a1.y + p2*b1.y + p3*c1v.y + p4*e1.y;
        A1.z = A1.z*scale + p1*a1.z + p2*b1.z + p3*c1v.z + p4*e1.z;
        A1.w = A1.w*scale + p1*a1.w + p2*b1.w + p3*c1v.w + p4*e1.w;
        A2.x = A2.x*scale + p1*a2.x + p2*b2.x + p3*c2v.x + p4*e2.x;
        A2.y = A2.y*scale + p1*a2.y + p2*b2.y + p3*c2v.y + p4*e2.y;
        A2.z = A2.z*scale + p1*a2.z + p2*b2.z + p3*c2v.z + p4*e2.z;
        A2.w = A2.w*scale + p1*a2.w + p2*b2.w + p3*c2v.w + p4*e2.w;
        mloc = mnew;
    }
    for (; s + 16 < end; s += 32) {
        const float4* ra = (const float4*)(base + (size_t)s * DD);
        const float4* rb = (const float4*)(base + (size_t)(s + 16) * DD);
        float4 a0 = ra[lane], a1 = ra[lane + 64], a2 = ra[lane + 128];
        float4 b0 = rb[lane], b1 = rb[lane + 64], b2 = rb[lane + 128];
        float d1 = a0.x*mm0.x + a0.y*mm0.y + a0.z*mm0.z + a0.w*mm0.w
                 + a1.x*mm1.x + a1.y*mm1.y + a1.z*mm1.z + a1.w*mm1.w
                 + a2.x*mm2.x + a2.y*mm2.y + a2.z*mm2.z + a2.w*mm2.w;
        float d2 = b0.x*mm0.x + b0.y*mm0.y + b0.z*mm0.z + b0.w*mm0.w
                 + b1.x*mm1.x + b1.y*mm1.y + b1.z*mm1.z + b1.w*mm1.w
                 + b2.x*mm2.x + b2.y*mm2.y + b2.z*mm2.z + b2.w*mm2.w;
        #pragma unroll
        for (int off = 32; off > 0; off >>= 1) {    // 2-way interleaved reduce
            d1 += __shfl_xor(d1, off, 64);
            d2 += __shfl_xor(d2, off, 64);
        }
        float mnew = fmaxf(mloc, fmaxf(d1, d2));
        float scale = __expf(mloc - mnew);
        float p1 = __expf(d1 - mnew);
        float p2 = __expf(d2 - mnew);
        lloc = lloc * scale + p1 + p2;
        A0.x = A0.x*scale + p1*a0.x + p2*b0.x; A0.y = A0.y*scale + p1*a0.y + p2*b0.y;
        A0.z = A0.z*scale + p1*a0.z + p2*b0.z; A0.w = A0.w*scale + p1*a0.w + p2*b0.w;
        A1.x = A1.x*scale + p1*a1.x + p2*b1.x; A1.y = A1.y*scale + p1*a1.y + p2*b1.y;
        A1.z = A1.z*scale + p1*a1.z + p2*b1.z; A1.w = A1.w*scale + p1*a1.w + p2*b1.w;
        A2.x = A2.x*scale + p1*a2.x + p2*b2.x; A2.y = A2.y*scale + p1*a2.y + p2*b2.y;
        A2.z = A2.z*scale + p1*a2.z + p2*b2.z; A2.w = A2.w*scale + p1*a2.w + p2*b2.w;
        mloc = mnew;
    }
    for (; s < end; s += 16) {
        const float4* ra = (const float4*)(base + (size_t)s * DD);
        float4 a0 = ra[lane], a1 = ra[lane + 64], a2 = ra[lane + 128];
        float d1 = a0.x*mm0.x + a0.y*mm0.y + a0.z*mm0.z + a0.w*mm0.w
                 + a1.x*mm1.x + a1.y*mm1.y + a1.z*mm1.z + a1.w*mm1.w
                 + a2.x*mm2.x + a2.y*mm2.y + a2.z*mm2.z + a2.w*mm2.w;
        #pragma unroll
        for (int off = 32; off > 0; off >>= 1) d1 += __shfl_xor(d1, off, 64);
        float mnew = fmaxf(mloc, d1);
        float scale = __expf(mloc - mnew);
        float p1 = __expf(d1 - mnew);
        lloc = lloc * scale + p1;
        A0.x = A0.x*scale + p1*a0.x; A0.y = A0.y*scale + p1*a0.y;
        A0.z = A0.z*scale + p1*a0.z; A0.w = A0.w*scale + p1*a0.w;
        A1.x = A1.x*scale + p1*a1.x; A1.y = A1.y*scale + p1*a1.y;
        A1.z = A1.z*scale + p1*a1.z; A1.w = A1.w*scale + p1*a1.w;
        A2.x = A2.x*scale + p1*a2.x; A2.y = A2.y*scale + p1*a2.y;
        A2.z = A2.z*scale + p1*a2.z; A2.w = A2.w*scale + p1*a2.w;
        mloc = mnew;
    }
    if (lane == 0) { s_m[wave] = mloc; s_l[wave] = lloc; }
    float4* pw = (float4*)s_part[wave];
    pw[lane] = A0; pw[lane + 64] = A1; pw[lane + 128] = A2;
    __syncthreads();

    // combine 16 wave-partials
    if (tid == 0) {
        float M = -INFINITY;
        #pragma unroll
        for (int w = 0; w < 16; ++w) M = fmaxf(M, s_m[w]);
        s_M = M;
    }
    __syncthreads();
    if (tid < 16) s_scale[tid] = __expf(s_m[tid] - s_M);  // empty wave -> 0
    __syncthreads();

    if (tid < DD) {
        float lt = 0.f, a = 0.f;
        #pragma unroll
        for (int w = 0; w < 16; ++w) {
            lt += s_scale[w] * s_l[w];
            a  += s_scale[w] * s_part[w][tid];
        }
        unsigned short* fb = feats + (size_t)b * K2;
        fb[tid]      = f2bf(a / lt);
        fb[DD + tid] = f2bf(s_mask[tid]);
    }
}

// Kernel 2 (MFMA): h[b][j] = tanh(feats[b][:] . dw[j][:] + db[j])
// 512 thr: wave-quads cover 32x32 tile, wave-pairs split K (24 MFMAs each,
// half the serial chain), LDS combine. (R1-verified)
__global__ __launch_bounds__(512) void k_dense(
    const unsigned short* __restrict__ featsb,
    const unsigned short* __restrict__ dwb,
    const float* __restrict__ db, float* __restrict__ h)
{
    __shared__ floatx4 s_acc[4][64];
    const int tid = threadIdx.x;
    const int lane = tid & 63, wave = tid >> 6;   // 0..7
    const int wq = wave & 3, kh = wave >> 2;
    const int b0 = blockIdx.y * 32 + (wq >> 1) * 16;
    const int j0 = blockIdx.x * 32 + (wq & 1) * 16;
    const int m = lane & 15, q = lane >> 4;

    const short8* Arow = (const short8*)(featsb + (size_t)(b0 + m) * K2) + kh * 96;
    const short8* Brow = (const short8*)(dwb + (size_t)(j0 + m) * K2) + kh * 96;
    floatx4 acc = {0.f, 0.f, 0.f, 0.f};
    #pragma unroll 6
    for (int k8 = 0; k8 < 96; k8 += 4) {   // 24 iters, K-step 32
        short8 a = Arow[k8 + q];
        short8 w = Brow[k8 + q];
        acc = __builtin_amdgcn_mfma_f32_16x16x32_bf16(a, w, acc, 0, 0, 0);
    }
    if (kh) s_acc[wq][lane] = acc;
    __syncthreads();
    if (!kh) {
        floatx4 o = s_acc[wq][lane];
        acc.x += o.x; acc.y += o.y; acc.z += o.z; acc.w += o.w;
        const int col = j0 + m;           // C/D: col = lane&15
        const int rb = b0 + q * 4;        //      row = quad*4 + reg
        const float bias = db[col];
        #pragma unroll
        for (int r = 0; r < 4; ++r)
            h[(size_t)(rb + r) * DD + col] = tanhf(acc[r] + bias);
    }
}

// Kernel 3: 21 decoder rows + tanh + tiny (2 x {8,6,7}) matmuls.
// h fragments hoisted out of the row loop; float4 dec_w loads. (R1-verified)
__global__ __launch_bounds__(256) void k_dec(
    const float* __restrict__ h, const float* __restrict__ dec_w,
    const float* __restrict__ dec_b, const float* __restrict__ w0,
    const float* __restrict__ w1, const float* __restrict__ w2,
    float* __restrict__ out)   // out = d_out + B*2, layout [b][c][g]
{
    __shared__ __align__(16) float s_h[DD];
    __shared__ float s_p[21];
    const int b = blockIdx.x;
    const int tid = threadIdx.x;
    const int lane = tid & 63, wave = tid >> 6;

    for (int d = tid; d < DD; d += 256) s_h[d] = h[(size_t)b * DD + d];
    __syncthreads();

    const float4* h4 = (const float4*)s_h;
    float4 x0 = h4[lane], x1 = h4[lane + 64], x2 = h4[lane + 128];

    for (int idx = wave; idx < 21; idx += 4) {
        const int vid = c_ids[idx];
        const float4* wr = (const float4*)(dec_w + (size_t)vid * DD);
        float4 v0 = wr[lane], v1 = wr[lane + 64], v2 = wr[lane + 128];
        float acc = x0.x*v0.x + x0.y*v0.y + x0.z*v0.z + x0.w*v0.w
                  + x1.x*v1.x + x1.y*v1.y + x1.z*v1.z + x1.w*v1.w
                  + x2.x*v2.x + x2.y*v2.y + x2.z*v2.z + x2.w*v2.w;
        acc = waveReduceSum(acc);
        if (lane == 0) s_p[idx] = tanhf(acc + dec_b[vid]);
    }
    __syncthreads();

    if (tid < 6) {
        const int c = tid / 3, g = tid % 3;
        const float* wg = (g == 0) ? w0 : (g == 1) ? w1 : w2;
        const int n    = (g == 0) ? 8  : (g == 1) ? 6  : 7;
        const int base = (g == 0) ? 0  : (g == 1) ? 8  : 14;
        float acc = 0.f;
        for (int i = 0; i < n; ++i) acc += s_p[base + i] * wg[c * n + i];
        out[(size_t)b * 6 + c * 3 + g] = acc;
    }
}

extern "C" void kernel_launch(void* const* d_in, const int* in_sizes, int n_in,
                              void* d_out, int out_size, void* d_ws, size_t ws_size,
                              hipStream_t stream) {
    const float* bert    = (const float*)d_in[0];
    const int*   ids     = (const int*)  d_in[1];
    const int*   len     = (const int*)  d_in[2];
    const float* senti_w = (const float*)d_in[3];
    const float* senti_b = (const float*)d_in[4];
    const float* dense_w = (const float*)d_in[5];
    const float* dense_b = (const float*)d_in[6];
    const float* dec_w   = (const float*)d_in[7];
    const float* dec_b   = (const float*)d_in[8];
    const float* w0      = (const float*)d_in[9];
    const float* w1      = (const float*)d_in[10];
    const float* w2      = (const float*)d_in[11];
    float* out = (float*)d_out;

    // ws layout (16B aligned chunks)
    unsigned short* feats = (unsigned short*)d_ws;            // B x 1536 bf16
    unsigned short* dwb   = feats + (size_t)BB * K2;          // 768x1536 bf16
    float* h = (float*)(dwb + (size_t)DD * K2);               // B x 768 fp32

    k_att<<<BB, 1024, 0, stream>>>(bert, ids, len, senti_w, senti_b, out,
                                   feats, dense_w, dwb);
    k_dense<<<dim3(24, 8), 512, 0, stream>>>(feats, dwb, dense_b, h);
    k_dec<<<BB, 256, 0, stream>>>(h, dec_w, dec_b, w0, w1, w2, out + BB * 2);
}